// Round 2
// baseline (229.197 us; speedup 1.0000x reference)
//
#include <hip/hip_runtime.h>
#include <stdint.h>

// y[n,i] = relu(b[idx[n],i] + sum_o w[idx[n],i,o] * x[n,o])
// B=8192, 64 models, 256x256 fp32.
//
// R2 structure: 512 blocks (64 models x 2 sample-tiles x 4 out-tiles of 64),
// 512 threads (8 waves, 4m x 2n grid of 32x32 wave tiles). Only w staged in
// LDS (~34 KB -> 2 blocks/CU co-resident); x MFMA A-fragments loaded DIRECTLY
// from global via rid (removes the serial scan->x-stage->barrier chain; x
// fetch overlaps MFMA). XCD-bijective swizzle co-locates each model's 8
// blocks on one XCD so w/x re-reads hit local L2.
//
// Still REPEAT=8 diagnostic (1 more round of counter visibility): reps write
// identical outputs; per-location single-writer wave => rep-7 store is
// race-clean and program-ordered last => exact results.

#define N_MODELS 64
#define IN_F     256
#define OUT_F    256
#define BATCH    8192
#define BM       128   // sample rows per tile
#define BN       64    // out cols per block
#define PK       264   // LDS pitch (bf16): +8 shorts -> 4-bank row shift
#define REPEAT   8     // diagnostic multiplier

typedef __bf16 bf16x8 __attribute__((ext_vector_type(8)));
typedef float  f32x4  __attribute__((ext_vector_type(4)));

__device__ __forceinline__ bf16x8 pack8(float4 a, float4 b) {
  bf16x8 o;                       // native casts -> v_cvt_pk_bf16_f32
  o[0] = (__bf16)a.x; o[1] = (__bf16)a.y; o[2] = (__bf16)a.z; o[3] = (__bf16)a.w;
  o[4] = (__bf16)b.x; o[5] = (__bf16)b.y; o[6] = (__bf16)b.z; o[7] = (__bf16)b.w;
  return o;
}

__global__ __launch_bounds__(512) void fused_kernel(
    const float* __restrict__ x, const int* __restrict__ idxs,
    const float* __restrict__ w, const float* __restrict__ bias_g,
    float* __restrict__ out) {
  // XCD-bijective swizzle (512 % 8 == 0): blocks of one model -> one XCD
  const int b     = (blockIdx.x & 7) * 64 + (blockIdx.x >> 3);
  const int model = b >> 3;
  const int tile  = (b >> 2) & 1;
  const int i0    = (b & 3) * BN;
  const int t     = threadIdx.x;
  const int lane  = t & 63;
  const int wv    = t >> 6;          // 0..7

  __shared__ unsigned short b_lds[BN][PK];  // w rows, bf16
  __shared__ int rid[BM];
  __shared__ int wsum[8];

  const int rw = t >> 3;   // staged w row (8 threads/row), 0..63
  const int h  = t & 7;    // 32-float chunk within the row

  const float* wrow = w + (size_t)model * (IN_F * OUT_F)
                        + (size_t)(i0 + rw) * IN_F + h * 32;

  // wave tile coords
  const int wm   = (wv & 3) * 32;    // 4 m-tiles of 32 rows
  const int wn   = (wv >> 2) * 32;   // 2 n-tiles of 32 cols
  const int col  = lane & 15;
  const int quad = lane >> 4;

  for (int rep = 0; rep < REPEAT; ++rep) {
    asm volatile("" ::: "memory");   // no cross-rep CSE/hoist of loads

    // ---- idx loads first: latency-critical chain (scan depends on them) ----
    const int4* ip = (const int4*)idxs + t * 4;   // 16 idxs/thread
    int4 iv0 = ip[0], iv1 = ip[1], iv2 = ip[2], iv3 = ip[3];

    // ---- w staging, unconditional, issued at t0 (overlaps idx+scan) ----
    {
      float4 tw[8];
#pragma unroll
      for (int j = 0; j < 8; ++j) tw[j] = *(const float4*)(wrow + j * 4);
#pragma unroll
      for (int j = 0; j < 4; ++j)
        *(bf16x8*)&b_lds[rw][h * 32 + j * 8] = pack8(tw[2 * j], tw[2 * j + 1]);
    }

    if (t < BM) rid[t] = -1;

    // bias (tiny, issue early)
    float bv[2];
    const float* bp = bias_g + model * OUT_F + i0 + wn + col;
#pragma unroll
    for (int nt = 0; nt < 2; ++nt) bv[nt] = bp[nt * 16];

    // ---- compaction: thread t owns idxs[16t .. 16t+15] ----
    int cnt = (iv0.x == model) + (iv0.y == model) + (iv0.z == model) + (iv0.w == model)
            + (iv1.x == model) + (iv1.y == model) + (iv1.z == model) + (iv1.w == model)
            + (iv2.x == model) + (iv2.y == model) + (iv2.z == model) + (iv2.w == model)
            + (iv3.x == model) + (iv3.y == model) + (iv3.z == model) + (iv3.w == model);
    int inc = cnt;
#pragma unroll
    for (int d = 1; d < 64; d <<= 1) {
      int u = __shfl_up(inc, d);
      if (lane >= d) inc += u;
    }
    if (lane == 63) wsum[wv] = inc;
    __syncthreads();
    int wpre = 0, total = 0;
#pragma unroll
    for (int j = 0; j < 8; ++j) {
      int s = wsum[j];
      total += s;
      if (j < wv) wpre += s;
    }
    const int start = tile * BM;
    if (start >= total) break;       // block-uniform; empty tile exits
    int off = wpre + inc - cnt - start;
    {
      int n0 = t * 16;
      if (iv0.x == model) { if ((unsigned)off < BM) rid[off] = n0 + 0;  ++off; }
      if (iv0.y == model) { if ((unsigned)off < BM) rid[off] = n0 + 1;  ++off; }
      if (iv0.z == model) { if ((unsigned)off < BM) rid[off] = n0 + 2;  ++off; }
      if (iv0.w == model) { if ((unsigned)off < BM) rid[off] = n0 + 3;  ++off; }
      if (iv1.x == model) { if ((unsigned)off < BM) rid[off] = n0 + 4;  ++off; }
      if (iv1.y == model) { if ((unsigned)off < BM) rid[off] = n0 + 5;  ++off; }
      if (iv1.z == model) { if ((unsigned)off < BM) rid[off] = n0 + 6;  ++off; }
      if (iv1.w == model) { if ((unsigned)off < BM) rid[off] = n0 + 7;  ++off; }
      if (iv2.x == model) { if ((unsigned)off < BM) rid[off] = n0 + 8;  ++off; }
      if (iv2.y == model) { if ((unsigned)off < BM) rid[off] = n0 + 9;  ++off; }
      if (iv2.z == model) { if ((unsigned)off < BM) rid[off] = n0 + 10; ++off; }
      if (iv2.w == model) { if ((unsigned)off < BM) rid[off] = n0 + 11; ++off; }
      if (iv3.x == model) { if ((unsigned)off < BM) rid[off] = n0 + 12; ++off; }
      if (iv3.y == model) { if ((unsigned)off < BM) rid[off] = n0 + 13; ++off; }
      if (iv3.z == model) { if ((unsigned)off < BM) rid[off] = n0 + 14; ++off; }
      if (iv3.w == model) { if ((unsigned)off < BM) rid[off] = n0 + 15; ++off; }
    }
    __syncthreads();                 // rid + b_lds ready; only barrier pair

    // ---- per-lane x row pointers for A-fragments (direct global) ----
    int sr0 = rid[wm + col];
    int sr1 = rid[wm + 16 + col];
    const float* xr0 = x + (size_t)(sr0 < 0 ? 0 : sr0) * IN_F + quad * 8;
    const float* xr1 = x + (size_t)(sr1 < 0 ? 0 : sr1) * IN_F + quad * 8;

    f32x4 acc[2][2];                 // bias folded into acc init
#pragma unroll
    for (int mt = 0; mt < 2; ++mt)
#pragma unroll
      for (int nt = 0; nt < 2; ++nt)
        acc[mt][nt] = (f32x4){bv[nt], bv[nt], bv[nt], bv[nt]};

    // ---- 8 k-steps: A from global (latency overlapped by MFMA + 2 blk/CU),
    //      B from LDS, 4 MFMA per step ----
#pragma unroll
    for (int ks = 0; ks < 8; ++ks) {
      float4 a00 = *(const float4*)(xr0 + ks * 32);
      float4 a01 = *(const float4*)(xr0 + ks * 32 + 4);
      float4 a10 = *(const float4*)(xr1 + ks * 32);
      float4 a11 = *(const float4*)(xr1 + ks * 32 + 4);
      bf16x8 af[2];
      af[0] = pack8(a00, a01);
      af[1] = pack8(a10, a11);
      bf16x8 bfr[2];
#pragma unroll
      for (int nt = 0; nt < 2; ++nt)
        bfr[nt] = *(const bf16x8*)&b_lds[wn + nt * 16 + col][ks * 32 + quad * 8];
#pragma unroll
      for (int mt = 0; mt < 2; ++mt)
#pragma unroll
        for (int nt = 0; nt < 2; ++nt)
          acc[mt][nt] = __builtin_amdgcn_mfma_f32_16x16x32_bf16(
              af[mt], bfr[nt], acc[mt][nt], 0, 0, 0);
    }

    // ---- epilogue: relu + scatter by sample id ----
#pragma unroll
    for (int mt = 0; mt < 2; ++mt) {
#pragma unroll
      for (int reg = 0; reg < 4; ++reg) {
        const int mm = wm + mt * 16 + quad * 4 + reg;   // C/D: row = quad*4+reg
        const int s = rid[mm];
        if (s >= 0) {
          float* orow = out + (size_t)s * OUT_F + i0 + wn + col;
#pragma unroll
          for (int nt = 0; nt < 2; ++nt)
            orow[nt * 16] = fmaxf(acc[mt][nt][reg], 0.0f);
        }
      }
    }
  }
}

extern "C" void kernel_launch(void* const* d_in, const int* in_sizes, int n_in,
                              void* d_out, int out_size, void* d_ws, size_t ws_size,
                              hipStream_t stream) {
  const float* x    = (const float*)d_in[0];
  const int*   idxs = (const int*)d_in[1];
  const float* w    = (const float*)d_in[2];
  const float* b    = (const float*)d_in[3];
  float* out = (float*)d_out;
  (void)d_ws; (void)ws_size;

  fused_kernel<<<N_MODELS * 8, 512, 0, stream>>>(x, idxs, w, b, out);
}

// Round 3
// 87.484 us; speedup vs baseline: 2.6199x; 2.6199x over previous
//
#include <hip/hip_runtime.h>
#include <stdint.h>

// y[n,i] = relu(b[idx[n],i] + sum_o w[idx[n],i,o] * x[n,o])
// B=8192, 64 models, 256x256 fp32.
//
// R3: two-kernel split.
//  A) compact_kernel: 64 blocks (1 per model) scan idx once, write compacted
//     sample ids (rid_g[64][256], -1-padded) + counts to workspace.
//  B) gemm_kernel: 256 blocks (64 models x 2 sample-tiles x 2 out-tiles),
//     1024 thr, R0's proven 128x128 tile / 16-wave 32x32 MFMA grid. No idx
//     read, no scan: staging threads load their OWN rid_g entry (8-lane
//     broadcast) -> x gather issues immediately, w staging independent,
//     ONE barrier, MFMA, relu+scatter. XCD-bijective swizzle keeps each
//     model's 4 blocks on one XCD for L2 reuse.

#define N_MODELS 64
#define IN_F     256
#define OUT_F    256
#define BATCH    8192
#define BM       128
#define BN       128
#define PK       264   // LDS pitch bf16: 256+8 -> rows shift 4 banks

typedef __bf16 bf16x8 __attribute__((ext_vector_type(8)));
typedef float  f32x4  __attribute__((ext_vector_type(4)));

__device__ __forceinline__ bf16x8 pack8(float4 a, float4 b) {
  bf16x8 o;                       // native casts -> v_cvt_pk_bf16_f32
  o[0] = (__bf16)a.x; o[1] = (__bf16)a.y; o[2] = (__bf16)a.z; o[3] = (__bf16)a.w;
  o[4] = (__bf16)b.x; o[5] = (__bf16)b.y; o[6] = (__bf16)b.z; o[7] = (__bf16)b.w;
  return o;
}

// ---- kernel A: per-model compaction into workspace ----
__global__ __launch_bounds__(1024) void compact_kernel(
    const int* __restrict__ idxs, int* __restrict__ rid_g,
    int* __restrict__ cnt_g) {
  const int model = blockIdx.x;
  const int t     = threadIdx.x;
  const int lane  = t & 63;
  const int wv    = t >> 6;          // 0..15
  __shared__ int wsum[16];

  const int4* ip = (const int4*)idxs + t * 2;   // 8 idxs/thread
  int4 iv0 = ip[0], iv1 = ip[1];

  int cnt = (iv0.x == model) + (iv0.y == model) + (iv0.z == model) + (iv0.w == model)
          + (iv1.x == model) + (iv1.y == model) + (iv1.z == model) + (iv1.w == model);
  int inc = cnt;
#pragma unroll
  for (int d = 1; d < 64; d <<= 1) {
    int u = __shfl_up(inc, d);
    if (lane >= d) inc += u;
  }
  if (lane == 63) wsum[wv] = inc;
  __syncthreads();
  int wpre = 0, total = 0;
#pragma unroll
  for (int j = 0; j < 16; ++j) {
    int s = wsum[j];
    total += s;
    if (j < wv) wpre += s;
  }
  int off = wpre + inc - cnt;
  int* rg = rid_g + model * 256;
  {
    int n0 = t * 8;
    if (iv0.x == model) { if ((unsigned)off < 256u) rg[off] = n0 + 0; ++off; }
    if (iv0.y == model) { if ((unsigned)off < 256u) rg[off] = n0 + 1; ++off; }
    if (iv0.z == model) { if ((unsigned)off < 256u) rg[off] = n0 + 2; ++off; }
    if (iv0.w == model) { if ((unsigned)off < 256u) rg[off] = n0 + 3; ++off; }
    if (iv1.x == model) { if ((unsigned)off < 256u) rg[off] = n0 + 4; ++off; }
    if (iv1.y == model) { if ((unsigned)off < 256u) rg[off] = n0 + 5; ++off; }
    if (iv1.z == model) { if ((unsigned)off < 256u) rg[off] = n0 + 6; ++off; }
    if (iv1.w == model) { if ((unsigned)off < 256u) rg[off] = n0 + 7; ++off; }
  }
  if (t < 256 && t >= total) rg[t] = -1;   // pad tail
  if (t == 0) cnt_g[model] = total;
}

// ---- kernel B: gathered GEMM, no scan ----
__global__ __launch_bounds__(1024) void gemm_kernel(
    const float* __restrict__ x, const float* __restrict__ w,
    const float* __restrict__ bias_g, float* __restrict__ out,
    const int* __restrict__ rid_g, const int* __restrict__ cnt_g) {
  // XCD-bijective swizzle (256 % 8 == 0): a model's 4 blocks -> one XCD
  const int b     = (blockIdx.x & 7) * 32 + (blockIdx.x >> 3);
  const int model = b >> 2;
  const int s     = (b >> 1) & 1;    // sample-tile (rows s*128 ..)
  const int i0    = (b & 1) * BN;    // out-col tile
  const int t     = threadIdx.x;
  const int lane  = t & 63;
  const int wv    = t >> 6;          // 0..15

  __shared__ unsigned short a_lds[BM][PK];  // gathered x rows, bf16
  __shared__ unsigned short b_lds[BN][PK];  // w rows, bf16
  __shared__ int rid[BM];

  const int total = cnt_g[model];
  if (s * BM >= total) return;       // block-uniform early exit

  // epilogue copy of rid (covered by the single pre-MFMA barrier)
  if (t < BM) rid[t] = rid_g[model * 256 + s * BM + t];

  const int rw = t >> 3;   // staged row (8 threads/row), 0..127
  const int h  = t & 7;    // 32-float chunk within the row

  // per-thread rid load (8-lane broadcast) -> x staging needs NO barrier
  const int srow = rid_g[model * 256 + s * BM + rw];

  // ---- w staging (independent of rid; issues under the rid roundtrip) ----
  const float* wrow = w + (size_t)model * (IN_F * OUT_F)
                        + (size_t)(i0 + rw) * IN_F + h * 32;
  {
    float4 tw[8];
#pragma unroll
    for (int j = 0; j < 8; ++j) tw[j] = *(const float4*)(wrow + j * 4);
#pragma unroll
    for (int j = 0; j < 4; ++j)
      *(bf16x8*)&b_lds[rw][h * 32 + j * 8] = pack8(tw[2 * j], tw[2 * j + 1]);
  }

  // ---- x staging (gathered rows; invalid rows read row 0, never stored) ----
  const float* xrow = x + (size_t)(srow < 0 ? 0 : srow) * IN_F + h * 32;
  {
    float4 tx[8];
#pragma unroll
    for (int j = 0; j < 8; ++j) tx[j] = *(const float4*)(xrow + j * 4);
#pragma unroll
    for (int j = 0; j < 4; ++j)
      *(bf16x8*)&a_lds[rw][h * 32 + j * 8] = pack8(tx[2 * j], tx[2 * j + 1]);
  }

  // wave tile coords + bias (issued while staging drains)
  const int wm   = (wv & 3) * 32;    // 4x4 wave grid of 32x32 tiles
  const int wn   = (wv >> 2) * 32;
  const int col  = lane & 15;
  const int quad = lane >> 4;
  float bv[2];
  const float* bp = bias_g + model * OUT_F + i0 + wn + col;
#pragma unroll
  for (int nt = 0; nt < 2; ++nt) bv[nt] = bp[nt * 16];

  __syncthreads();                   // ONLY barrier: tiles + rid ready

  f32x4 acc[2][2];                   // bias folded into acc init
#pragma unroll
  for (int mt = 0; mt < 2; ++mt)
#pragma unroll
    for (int nt = 0; nt < 2; ++nt)
      acc[mt][nt] = (f32x4){bv[nt], bv[nt], bv[nt], bv[nt]};

  // ---- 8 k-steps x 4 MFMA per wave, zero barriers ----
#pragma unroll
  for (int ks = 0; ks < 8; ++ks) {
    bf16x8 af[2], bfr[2];
#pragma unroll
    for (int mt = 0; mt < 2; ++mt)
      af[mt] = *(const bf16x8*)&a_lds[wm + mt * 16 + col][ks * 32 + quad * 8];
#pragma unroll
    for (int nt = 0; nt < 2; ++nt)
      bfr[nt] = *(const bf16x8*)&b_lds[wn + nt * 16 + col][ks * 32 + quad * 8];
#pragma unroll
    for (int mt = 0; mt < 2; ++mt)
#pragma unroll
      for (int nt = 0; nt < 2; ++nt)
        acc[mt][nt] = __builtin_amdgcn_mfma_f32_16x16x32_bf16(
            af[mt], bfr[nt], acc[mt][nt], 0, 0, 0);
  }

  // ---- epilogue: relu + scatter by sample id ----
#pragma unroll
  for (int mt = 0; mt < 2; ++mt) {
#pragma unroll
    for (int reg = 0; reg < 4; ++reg) {
      const int mm = wm + mt * 16 + quad * 4 + reg;   // C/D: row = quad*4+reg
      const int sle = rid[mm];
      if (sle >= 0) {
        float* orow = out + (size_t)sle * OUT_F + i0 + wn + col;
#pragma unroll
        for (int nt = 0; nt < 2; ++nt)
          orow[nt * 16] = fmaxf(acc[mt][nt][reg], 0.0f);
      }
    }
  }
}

extern "C" void kernel_launch(void* const* d_in, const int* in_sizes, int n_in,
                              void* d_out, int out_size, void* d_ws, size_t ws_size,
                              hipStream_t stream) {
  const float* x    = (const float*)d_in[0];
  const int*   idxs = (const int*)d_in[1];
  const float* w    = (const float*)d_in[2];
  const float* b    = (const float*)d_in[3];
  float* out = (float*)d_out;

  int* rid_g = (int*)d_ws;              // 64*256 ints
  int* cnt_g = rid_g + N_MODELS * 256;  // 64 ints

  compact_kernel<<<N_MODELS, 1024, 0, stream>>>(idxs, rid_g, cnt_g);
  gemm_kernel<<<N_MODELS * 4, 1024, 0, stream>>>(x, w, b, out, rid_g, cnt_g);
}